// Round 1
// baseline (236.433 us; speedup 1.0000x reference)
//
#include <hip/hip_runtime.h>
#include <math.h>

#define NEG_SLOPE 0.2f
#define LN_EPS 1e-5f

// ---------------- K0: sum of edge_attr (EDGE_DIM=1) ----------------
__global__ void ea_sum_kernel(const float* __restrict__ ea, float* __restrict__ out, int E) {
    int i = blockIdx.x * blockDim.x + threadIdx.x;
    int stride = gridDim.x * blockDim.x;
    float s = 0.f;
    for (int j = i; j < E; j += stride) s += ea[j];
#pragma unroll
    for (int o = 32; o >= 1; o >>= 1) s += __shfl_xor(s, o);
    if ((threadIdx.x & 63) == 0) atomicAdd(out, s);
}

// ---------------- K1: x_l = x@Wl+bl, x_r = x@Wr+br  (8 nodes/block) ----------------
__global__ __launch_bounds__(256) void transform_kernel(
    const float* __restrict__ x, const float* __restrict__ Wl, const float* __restrict__ bl,
    const float* __restrict__ Wr, const float* __restrict__ br,
    float* __restrict__ xl, float* __restrict__ xr, int n) {
    __shared__ float xs[8][64];
    int nb = blockIdx.x * 8;
    int rows = n - nb; if (rows > 8) rows = 8;
    int t = threadIdx.x;
    for (int i = t; i < rows * 64; i += 256) xs[i >> 6][i & 63] = x[(size_t)nb * 64 + i];
    __syncthreads();
    int o = t;  // output column 0..255
    float blv = bl[o], brv = br[o];
    float accl[8], accr[8];
#pragma unroll
    for (int i = 0; i < 8; ++i) { accl[i] = blv; accr[i] = brv; }
#pragma unroll 4
    for (int k = 0; k < 64; ++k) {
        float wl = Wl[k * 256 + o], wr = Wr[k * 256 + o];
#pragma unroll
        for (int i = 0; i < 8; ++i) { accl[i] += xs[i][k] * wl; accr[i] += xs[i][k] * wr; }
    }
    for (int i = 0; i < rows; ++i) {
        xl[(size_t)(nb + i) * 256 + o] = accl[i];
        xr[(size_t)(nb + i) * 256 + o] = accr[i];
    }
}

// ---------------- K2: in-degree count (real edges only) ----------------
__global__ void count_kernel(const int* __restrict__ ei, int* __restrict__ deg, int E) {
    int i = blockIdx.x * blockDim.x + threadIdx.x;
    if (i < E) atomicAdd(&deg[ei[E + i]], 1);
}

// ---------------- K3: exclusive scan of deg -> off (single block) ----------------
__global__ __launch_bounds__(256) void scan_kernel(const int* __restrict__ deg, int* __restrict__ off, int n) {
    __shared__ int part[256];
    __shared__ int spart[257];
    int t = threadIdx.x;
    int C = (n + 255) / 256;
    int lo = t * C, hi = lo + C; if (hi > n) hi = n; if (lo > n) lo = n;
    int s = 0;
    for (int i = lo; i < hi; ++i) s += deg[i];
    part[t] = s;
    __syncthreads();
    if (t == 0) {
        int acc = 0;
        for (int i = 0; i < 256; ++i) { spart[i] = acc; acc += part[i]; }
        spart[256] = acc;
    }
    __syncthreads();
    int base = spart[t];
    for (int i = lo; i < hi; ++i) { off[i] = base; base += deg[i]; }
    if (t == 0) off[n] = spart[256];
}

// ---------------- K4: fill CSR ----------------
__global__ void fill_kernel(const int* __restrict__ ei, const float* __restrict__ ea,
                            const int* __restrict__ off, int* __restrict__ cursor,
                            int* __restrict__ csr_src, float* __restrict__ csr_ea, int E) {
    int i = blockIdx.x * blockDim.x + threadIdx.x;
    if (i < E) {
        int d = ei[E + i];
        int pos = atomicAdd(&cursor[d], 1);
        int idx = off[d] + pos;
        csr_src[idx] = ei[i];
        csr_ea[idx] = ea[i];
    }
}

// ---------------- K5: per-destination-node GATv2 (wave per node, online softmax) ----------------
__global__ __launch_bounds__(256) void gat_kernel(
    const float* __restrict__ xl, const float* __restrict__ xr,
    const int* __restrict__ off, const int* __restrict__ csr_src, const float* __restrict__ csr_ea,
    const float* __restrict__ att, const float* __restrict__ We, const float* __restrict__ bias_conv,
    const float* __restrict__ ea_sum, float* __restrict__ hgat, int n, float inv_e) {
    int wid = (blockIdx.x * blockDim.x + threadIdx.x) >> 6;
    int lane = threadIdx.x & 63;
    if (wid >= n) return;
    const float ea_mean = ea_sum[0] * inv_e;

    const float4* xl4 = reinterpret_cast<const float4*>(xl);
    float4 xr4 = reinterpret_cast<const float4*>(xr)[(size_t)wid * 64 + lane];
    float4 att4 = reinterpret_cast<const float4*>(att)[lane];
    float4 We4  = reinterpret_cast<const float4*>(We)[lane];

    float M = -INFINITY, S = 0.f;
    float4 acc = make_float4(0.f, 0.f, 0.f, 0.f);

    auto process = [&](int s, float a) {
        float4 v = xl4[(size_t)s * 64 + lane];
        float m0 = v.x + xr4.x + a * We4.x; m0 = m0 > 0.f ? m0 : NEG_SLOPE * m0;
        float m1 = v.y + xr4.y + a * We4.y; m1 = m1 > 0.f ? m1 : NEG_SLOPE * m1;
        float m2 = v.z + xr4.z + a * We4.z; m2 = m2 > 0.f ? m2 : NEG_SLOPE * m2;
        float m3 = v.w + xr4.w + a * We4.w; m3 = m3 > 0.f ? m3 : NEG_SLOPE * m3;
        float p = m0 * att4.x + m1 * att4.y + m2 * att4.z + m3 * att4.w;
        // reduce over the 16-lane head group (lanes differ only in low 4 bits)
        p += __shfl_xor(p, 1);
        p += __shfl_xor(p, 2);
        p += __shfl_xor(p, 4);
        p += __shfl_xor(p, 8);
        if (p > M) {
            float sc = expf(M - p);   // M=-inf on first edge -> sc=0
            S = S * sc + 1.f;
            acc.x = acc.x * sc + v.x;
            acc.y = acc.y * sc + v.y;
            acc.z = acc.z * sc + v.z;
            acc.w = acc.w * sc + v.w;
            M = p;
        } else {
            float w = expf(p - M);
            S += w;
            acc.x += w * v.x;
            acc.y += w * v.y;
            acc.z += w * v.z;
            acc.w += w * v.w;
        }
    };

    // self-loop (edge_attr = mean of real edge attrs)
    process(wid, ea_mean);
    int e0 = off[wid], e1 = off[wid + 1];
    for (int e = e0; e < e1; ++e) {
        process(csr_src[e], csr_ea[e]);
    }

    float inv = 1.f / (S + 1e-16f);
    float4 bc = reinterpret_cast<const float4*>(bias_conv)[lane];
    float4 o;
    o.x = acc.x * inv + bc.x;
    o.y = acc.y * inv + bc.y;
    o.z = acc.z * inv + bc.z;
    o.w = acc.w * inv + bc.w;
    reinterpret_cast<float4*>(hgat)[(size_t)wid * 64 + lane] = o;
}

// ---------------- K6: proj(256->64) + residual + ELU + LayerNorm ----------------
__global__ __launch_bounds__(256) void proj_ln_kernel(
    const float* __restrict__ hgat, const float* __restrict__ Wp, const float* __restrict__ bp,
    const float* __restrict__ x, const float* __restrict__ gamma, const float* __restrict__ beta,
    float* __restrict__ out, int n) {
    __shared__ float wp_s[256 * 64];   // 64 KB
    __shared__ float hbuf[4][256];
    for (int i = threadIdx.x; i < 256 * 64; i += 256) wp_s[i] = Wp[i];
    __syncthreads();
    int wave = threadIdx.x >> 6, lane = threadIdx.x & 63;
    int waves_total = gridDim.x * 4;
    float bpv = bp[lane], gv = gamma[lane], bv = beta[lane];
    for (int nidx = blockIdx.x * 4 + wave; nidx < n; nidx += waves_total) {
        float4 hv = reinterpret_cast<const float4*>(hgat)[(size_t)nidx * 64 + lane];
        reinterpret_cast<float4*>(hbuf[wave])[lane] = hv;   // wave-private buffer, no barrier needed
        float acc = bpv;
#pragma unroll 4
        for (int k = 0; k < 256; ++k) acc += hbuf[wave][k] * wp_s[k * 64 + lane];
        // residual + ELU
        float h = acc + x[(size_t)nidx * 64 + lane];
        h = h > 0.f ? h : expm1f(h);
        // LayerNorm over 64 lanes
        float s = h;
#pragma unroll
        for (int o = 32; o >= 1; o >>= 1) s += __shfl_xor(s, o);
        float mu = s * (1.f / 64.f);
        float d = h - mu;
        float s2 = d * d;
#pragma unroll
        for (int o = 32; o >= 1; o >>= 1) s2 += __shfl_xor(s2, o);
        float var = s2 * (1.f / 64.f);
        out[(size_t)nidx * 64 + lane] = d * rsqrtf(var + LN_EPS) * gv + bv;
    }
}

// ---------------- launcher ----------------
extern "C" void kernel_launch(void* const* d_in, const int* in_sizes, int n_in,
                              void* d_out, int out_size, void* d_ws, size_t ws_size,
                              hipStream_t stream) {
    const float* x         = (const float*)d_in[0];
    const int*   ei        = (const int*)d_in[1];
    const float* ea        = (const float*)d_in[2];
    const float* Wl        = (const float*)d_in[3];
    const float* bl        = (const float*)d_in[4];
    const float* Wr        = (const float*)d_in[5];
    const float* br        = (const float*)d_in[6];
    const float* We        = (const float*)d_in[7];
    const float* att       = (const float*)d_in[8];
    const float* bias_conv = (const float*)d_in[9];
    const float* Wp        = (const float*)d_in[10];
    const float* bp        = (const float*)d_in[11];
    const float* gamma     = (const float*)d_in[12];
    const float* beta      = (const float*)d_in[13];
    float* out = (float*)d_out;

    int N = in_sizes[0] / 64;   // 20000
    int E = in_sizes[2];        // 320000 (EDGE_DIM=1)

    char* w = (char*)d_ws;
    auto alloc = [&](size_t bytes) {
        char* p = w;
        w += (bytes + 255) & ~(size_t)255;
        return p;
    };
    float* xl      = (float*)alloc((size_t)N * 256 * 4);
    float* xr      = (float*)alloc((size_t)N * 256 * 4);
    float* hg      = (float*)alloc((size_t)N * 256 * 4);
    int*   csr_src = (int*)  alloc((size_t)E * 4);
    float* csr_ea  = (float*)alloc((size_t)E * 4);
    int*   deg     = (int*)  alloc((size_t)N * 4);
    int*   off     = (int*)  alloc((size_t)(N + 1) * 4);
    int*   cursor  = (int*)  alloc((size_t)N * 4);
    float* easum   = (float*)alloc(4);

    hipMemsetAsync(deg, 0, (size_t)N * 4, stream);
    hipMemsetAsync(cursor, 0, (size_t)N * 4, stream);
    hipMemsetAsync(easum, 0, 4, stream);

    ea_sum_kernel<<<256, 256, 0, stream>>>(ea, easum, E);
    transform_kernel<<<(N + 7) / 8, 256, 0, stream>>>(x, Wl, bl, Wr, br, xl, xr, N);
    count_kernel<<<(E + 255) / 256, 256, 0, stream>>>(ei, deg, E);
    scan_kernel<<<1, 256, 0, stream>>>(deg, off, N);
    fill_kernel<<<(E + 255) / 256, 256, 0, stream>>>(ei, ea, off, cursor, csr_src, csr_ea, E);
    gat_kernel<<<(N + 3) / 4, 256, 0, stream>>>(xl, xr, off, csr_src, csr_ea, att, We, bias_conv,
                                                easum, hg, N, 1.f / (float)E);
    proj_ln_kernel<<<512, 256, 0, stream>>>(hg, Wp, bp, x, gamma, beta, out, N);
}